// Round 12
// baseline (172.393 us; speedup 1.0000x reference)
//
#include <hip/hip_runtime.h>

typedef __bf16 bf16x8 __attribute__((ext_vector_type(8)));
typedef float f32x4 __attribute__((ext_vector_type(4)));

#define AS1 __attribute__((address_space(1)))
#define AS3 __attribute__((address_space(3)))

__device__ __forceinline__ void gload_lds16(const void* g, void* l) {
  __builtin_amdgcn_global_load_lds((const AS1 void*)g, (AS3 void*)l, 16, 0, 0);
}

#define MFMA16(a, b, c) __builtin_amdgcn_mfma_f32_16x16x32_bf16((a), (b), (c), 0, 0, 0)

// ---------------------------------------------------------------- fp32 -> bf16 (all 4 tensors, one dispatch)
__global__ __launch_bounds__(256)
void cvt_all(const float* __restrict__ sem, const float* __restrict__ wq,
             const float* __restrict__ wk, const float* __restrict__ wa,
             __bf16* __restrict__ semb, __bf16* __restrict__ wcat) {
  int i = blockIdx.x * 256 + threadIdx.x;
  if (i >= 2409472) return;
  const float* in;
  __bf16* out;
  int j;
  if (i < 1310720) { in = sem; out = semb; j = i; }
  else if (i < 1835008) { in = wq; out = wcat; j = i - 1310720; }
  else if (i < 2359296) { in = wk; out = wcat + 4194304; j = i - 1835008; }
  else { in = wa; out = wcat + 8388608; j = i - 2359296; }
  const float4* p = (const float4*)in;
  float4 a = p[2 * j], b = p[2 * j + 1];
  bf16x8 v;
  v[0] = (__bf16)a.x; v[1] = (__bf16)a.y; v[2] = (__bf16)a.z; v[3] = (__bf16)a.w;
  v[4] = (__bf16)b.x; v[5] = (__bf16)b.y; v[6] = (__bf16)b.z; v[7] = (__bf16)b.w;
  *(bf16x8*)(out + (size_t)j * 8) = v;
}

// ---------------------------------------------------------------- fused projection GEMM, 128x128, ring-3, counted vmcnt
// C[5120,4352] = semb[5120,2048] @ Wcat[4292,2048]^T (B rows clamped past 4291).
// cols [0,2048)->Qb bf16 +qb; [2048,4096)->Kb bf16 +kb; [4096,4292)->adj sigmoid.
// 256 thr = 4 waves (2M x 2N), wave tile 64x64 (acc[4][4]). BK=32, 64 iters.
// LDS = 3 ring slots x 16 KiB = 48 KiB -> 3 blocks/CU (max TLP so far).
// T4 schedule: iter j reads slot j%3, stages tile j+2 into slot (j+2)%3 (4 loads/thread,
// uniform), end-of-iter vmcnt(4) forces tile j+1 (issued a FULL iter ago -> latency
// covered) and leaves tile j+2's 4 loads in flight. Never drains to 0 mid-loop.
// BK=32 chunk-XOR swizzle (read chunk ^= row&3; global source pre-swizzled to match).
__global__ __launch_bounds__(256, 3)
void gemm_fused(const __bf16* __restrict__ A, const __bf16* __restrict__ B,
                const float* __restrict__ qbias, const float* __restrict__ kbias,
                const float* __restrict__ abias, __bf16* __restrict__ Qo,
                __bf16* __restrict__ Ko, float* __restrict__ adj) {
  __shared__ char smem[49152];  // 3 slots x (A 8K + B 8K)
  char* smc = smem;
  // bijective XCD chunking (nwg=1360 = 8 x 170 exact) + 8-wide tn-band, tm-major in band
  const int bid = blockIdx.x;
  const int wgid = (bid & 7) * 170 + (bid >> 3);
  int tm, tn;
  if (wgid < 1280) {
    const int band = wgid / 320, rem = wgid % 320;
    tm = rem >> 3;
    tn = band * 8 + (rem & 7);
  } else {
    const int rem = wgid - 1280;
    tm = rem >> 1;
    tn = 32 + (rem & 1);
  }

  const int t = threadIdx.x;
  const int lane = t & 63;
  const int w = t >> 6, wm = w >> 1, wn = w & 1;  // 4 waves: 2M x 2N, wave tile 64x64

  // ---- staging constants: 4 loads/thread/tile (A rows r,r+64; B rows r,r+64)
  // LDS linear dest; chunk swizzle folded into global source column.
  const int r0 = t >> 2;                          // 0..63
  const int gch = ((t & 3) ^ (r0 & 3)) * 8;       // pre-swizzled source chunk (elements)
  const __bf16* gA0 = A + (size_t)(tm * 128 + r0) * 2048 + gch;
  const __bf16* gA1 = gA0 + (size_t)64 * 2048;
  int br0 = tn * 128 + r0;       br0 = br0 < 4292 ? br0 : 4291;
  int br1 = tn * 128 + 64 + r0;  br1 = br1 < 4292 ? br1 : 4291;
  const __bf16* gB0 = B + (size_t)br0 * 2048 + gch;
  const __bf16* gB1 = B + (size_t)br1 * 2048 + gch;
  const int t16 = t * 16;

#define STAGE(kk, sb) do {                                  \
    char* dst = smc + (sb) + t16;                           \
    gload_lds16(gA0 + (kk) * 32, dst);                      \
    gload_lds16(gA1 + (kk) * 32, dst + 4096);               \
    gload_lds16(gB0 + (kk) * 32, dst + 8192);               \
    gload_lds16(gB1 + (kk) * 32, dst + 12288);              \
  } while (0)

  // ---- fragment-read constants (swizzled chunk: chunk' = (lane>>4) ^ (L&3))
  const int L = lane & 15;
  const int xch = (((lane >> 4) ^ (L & 3)) << 4);
  const int arb = (wm * 64 + L) * 64 + xch;           // + m*1024 (+slot)
  const int brb = 8192 + (wn * 64 + L) * 64 + xch;    // + n*1024 (+slot)

  f32x4 acc[4][4];
#pragma unroll
  for (int m = 0; m < 4; ++m)
#pragma unroll
    for (int n = 0; n < 4; ++n) acc[m][n] = (f32x4){0.f, 0.f, 0.f, 0.f};

  // prologue: tiles 0,1 -> slots 0,1; force tile 0 (leave tile 1's 4 loads in flight)
  STAGE(0, 0);
  STAGE(1, 16384);
  asm volatile("s_waitcnt vmcnt(4)" ::: "memory");
  __builtin_amdgcn_s_barrier();

  int cs = 0, ss = 32768;  // compute slot (tile j), stage slot (tile j+2)
  for (int j = 0; j < 64; ++j) {
    bf16x8 af[4], bf[4];
#pragma unroll
    for (int m = 0; m < 4; ++m) af[m] = *(const bf16x8*)(smc + cs + arb + m * 1024);
#pragma unroll
    for (int n = 0; n < 4; ++n) bf[n] = *(const bf16x8*)(smc + cs + brb + n * 1024);
    if (j < 62) STAGE(j + 2, ss);
    __builtin_amdgcn_s_setprio(1);
#pragma unroll
    for (int m = 0; m < 4; ++m)
#pragma unroll
      for (int n = 0; n < 4; ++n) acc[m][n] = MFMA16(af[m], bf[n], acc[m][n]);
    __builtin_amdgcn_s_setprio(0);
    // counted wait: force tile j+1 (issued a full iter ago); leave tile j+2 in flight
    if (j < 62) asm volatile("s_waitcnt vmcnt(4)" ::: "memory");
    else if (j == 62) asm volatile("s_waitcnt vmcnt(0)" ::: "memory");
    __builtin_amdgcn_s_barrier();
    cs = (cs == 32768) ? 0 : cs + 16384;
    ss = (ss == 32768) ? 0 : ss + 16384;
  }
  __syncthreads();

  // ---- epilogue
  if (tn < 32) {
    // bias-add + bf16 into LDS [128][136], then coalesced 16B row-major stores
    __bf16* so = (__bf16*)smc;
    const float* bias = (tn < 16) ? (qbias + tn * 128) : (kbias + (tn - 16) * 128);
#pragma unroll
    for (int n = 0; n < 4; ++n) {
      const int colb = wn * 64 + n * 16 + L;
      const float bv = bias[colb];
#pragma unroll
      for (int m = 0; m < 4; ++m) {
        const int rw = wm * 64 + m * 16 + (lane >> 4) * 4;
#pragma unroll
        for (int jj = 0; jj < 4; ++jj)
          so[(rw + jj) * 136 + colb] = (__bf16)(acc[m][n][jj] + bv);
      }
    }
    __syncthreads();
    __bf16* dst = (tn < 16) ? (Qo + tn * 128) : (Ko + (tn - 16) * 128);
    for (int idx = t; idx < 2048; idx += 256) {  // 128 rows x 16 16B-chunks
      const int row = idx >> 4, c = idx & 15;
      const int grow = tm * 128 + row;  // 40*128 = 5120 exact, no clamp
      bf16x8 v = *(const bf16x8*)(so + row * 136 + c * 8);
      *(bf16x8*)(dst + (size_t)grow * 2048 + c * 8) = v;
    }
  } else {
    // adj region (cols 4096..4291): scattered f32 sigmoid stores (small)
#pragma unroll
    for (int n = 0; n < 4; ++n) {
      const int colg = (tn - 32) * 128 + wn * 64 + n * 16 + L;
      if (colg < 196) {
        const float bv = abias[colg];
#pragma unroll
        for (int m = 0; m < 4; ++m)
#pragma unroll
          for (int jj = 0; jj < 4; ++jj) {
            const int row = tm * 128 + wm * 64 + m * 16 + (lane >> 4) * 4 + jj;
            const float v = acc[m][n][jj] + bv;
            adj[(size_t)row * 196 + colg] = 1.f / (1.f + __expf(-v));
          }
      }
    }
  }
#undef STAGE
}

// ---------------------------------------------------------------- attention 1/3: partial S
// grid (64 b x 8 kq): S_part[b][kq] = Q_b[:, kq*256..+256] @ K_b[...]^T  (f32 80x80)
__global__ __launch_bounds__(256)
void attn_s(const __bf16* __restrict__ Qb, const __bf16* __restrict__ Kb,
            float* __restrict__ Spart) {
  __shared__ char smem[81920];
  __bf16* sQ = (__bf16*)smem;            // [80][256]
  __bf16* sK = (__bf16*)(smem + 40960);  // [80][256]
  const int b = blockIdx.x >> 3, kq = blockIdx.x & 7;
  const int kc = kq * 256;
  const int t = threadIdx.x, lane = t & 63, w = t >> 6;
  const __bf16* Qbase = Qb + (size_t)b * 163840;
  const __bf16* Kbase = Kb + (size_t)b * 163840;

#pragma unroll
  for (int s = 0; s < 10; ++s) {
    const int i = t + s * 256;
    const int row = i >> 5, cb = i & 31;
    gload_lds16(Qbase + (size_t)row * 2048 + kc + cb * 8, sQ + i * 8);
  }
#pragma unroll
  for (int s = 0; s < 10; ++s) {
    const int i = t + s * 256;
    const int row = i >> 5, cb = i & 31;
    gload_lds16(Kbase + (size_t)row * 2048 + kc + cb * 8, sK + i * 8);
  }
  __syncthreads();

  f32x4 acc[7];
#pragma unroll
  for (int u = 0; u < 7; ++u) acc[u] = (f32x4){0.f, 0.f, 0.f, 0.f};
#pragma unroll
  for (int u = 0; u < 7; ++u) {
    const int tl = w + u * 4;
    if (tl < 25) {
      const int qi = tl / 5, kj = tl % 5;
#pragma unroll
      for (int k0 = 0; k0 < 256; k0 += 32) {
        bf16x8 a = *(const bf16x8*)(sQ + (qi * 16 + (lane & 15)) * 256 + k0 + (lane >> 4) * 8);
        bf16x8 kk = *(const bf16x8*)(sK + (kj * 16 + (lane & 15)) * 256 + k0 + (lane >> 4) * 8);
        acc[u] = MFMA16(a, kk, acc[u]);
      }
    }
  }
  float* Sp = Spart + (size_t)(b * 8 + kq) * 6400;
#pragma unroll
  for (int u = 0; u < 7; ++u) {
    const int tl = w + u * 4;
    if (tl < 25) {
      const int qi = tl / 5, kj = tl % 5;
#pragma unroll
      for (int jj = 0; jj < 4; ++jj) {
        const int r = qi * 16 + (lane >> 4) * 4 + jj;
        const int c = kj * 16 + (lane & 15);
        Sp[r * 80 + c] = acc[u][jj];
      }
    }
  }
}

// ---------------------------------------------------------------- attention 2/3: softmax
// grid 64: sum 8 partials, softmax(S*scale*mask), write P bf16 [80][96] (zero-padded)
__global__ __launch_bounds__(256)
void attn_soft(const float* __restrict__ Spart, const float* __restrict__ mask,
               __bf16* __restrict__ Pg) {
  __shared__ float S[80 * 81];
  const int b = blockIdx.x, t = threadIdx.x;
  const float* Sp = Spart + (size_t)b * 8 * 6400;
  for (int idx = t; idx < 6400; idx += 256) {
    float s = 0.f;
#pragma unroll
    for (int p = 0; p < 8; ++p) s += Sp[p * 6400 + idx];
    const int r = idx / 80, c = idx - r * 80;
    S[r * 81 + c] = s;
  }
  __syncthreads();
  if (t < 80) {
    const float scale = 0.02209708691207961f;  // 1/sqrt(2048)
    float mx = -1e30f;
    for (int k = 0; k < 80; ++k) {
      float v = S[t * 81 + k] * scale * mask[t * 80 + k];
      S[t * 81 + k] = v;
      mx = fmaxf(mx, v);
    }
    float sum = 0.f;
    for (int k = 0; k < 80; ++k) {
      float e = __expf(S[t * 81 + k] - mx);
      S[t * 81 + k] = e;
      sum += e;
    }
    const float r = 1.f / sum;
    __bf16* Pr = Pg + (size_t)b * 7680 + t * 96;
    for (int k = 0; k < 80; ++k) Pr[k] = (__bf16)(S[t * 81 + k] * r);
    for (int k = 80; k < 96; ++k) Pr[k] = (__bf16)0.f;
  }
}

// ---------------------------------------------------------------- attention 3/3: PV + epilogue
__global__ __launch_bounds__(256)
void attn_pv(const __bf16* __restrict__ Pg, const float* __restrict__ feats,
             const float* __restrict__ adj, float* __restrict__ out) {
  __shared__ __bf16 Ft[64 * 104];
  const int b = blockIdx.x >> 2, hq = blockIdx.x & 3;
  const int hb = hq * 49;
  const int t = threadIdx.x, lane = t & 63, w = t >> 6;
  for (int idx = t; idx < 4704; idx += 256) {  // 96*49
    const int k = idx / 49, h = idx - k * 49;
    Ft[h * 104 + k] = (k < 80) ? (__bf16)feats[(size_t)b * 15680 + k * 196 + hb + h]
                               : (__bf16)0.f;
  }
  __syncthreads();
  const __bf16* Pb = Pg + (size_t)b * 7680;
#pragma unroll
  for (int u = 0; u < 5; ++u) {
    const int tl = w + u * 4;  // 0..19
    const int ci = tl >> 2, hj = tl & 3;
    f32x4 a2 = (f32x4){0.f, 0.f, 0.f, 0.f};
#pragma unroll
    for (int k0 = 0; k0 < 96; k0 += 32) {
      bf16x8 pa = *(const bf16x8*)(Pb + (ci * 16 + (lane & 15)) * 96 + k0 + (lane >> 4) * 8);
      bf16x8 fb = *(const bf16x8*)(Ft + (hj * 16 + (lane & 15)) * 104 + k0 + (lane >> 4) * 8);
      a2 = MFMA16(pa, fb, a2);
    }
#pragma unroll
    for (int jj = 0; jj < 4; ++jj) {
      const int c = ci * 16 + (lane >> 4) * 4 + jj;
      const int h2 = hj * 16 + (lane & 15);
      if (h2 < 49) {
        const size_t o = (size_t)b * 15680 + (size_t)c * 196 + hb + h2;
        out[o] = (feats[o] + a2[jj]) * adj[o];
      }
    }
  }
}

// ---------------------------------------------------------------- launch
extern "C" void kernel_launch(void* const* d_in, const int* in_sizes, int n_in,
                              void* d_out, int out_size, void* d_ws, size_t ws_size,
                              hipStream_t stream) {
  const float* features = (const float*)d_in[0];
  const float* sem      = (const float*)d_in[1];
  const float* mask     = (const float*)d_in[2];
  const float* Wq_w     = (const float*)d_in[3];
  const float* Wq_b     = (const float*)d_in[4];
  const float* Wk_w     = (const float*)d_in[5];
  const float* Wk_b     = (const float*)d_in[6];
  const float* Wa_w     = (const float*)d_in[7];
  const float* Wa_b     = (const float*)d_in[8];
  float* out = (float*)d_out;

  char* ws = (char*)d_ws;
  __bf16* semb = (__bf16*)ws;                   // 5120x2048 bf16
  __bf16* wcat = (__bf16*)(ws + 20971520);      // 4292x2048 bf16
  __bf16* Qb   = (__bf16*)(ws + 38551552);
  __bf16* Kb   = (__bf16*)(ws + 59523072);
  float*  adj  = (float*)(ws + 80494592);       // 5120x196 f32 (total 84.5 MB)
  float*  Spart = (float*)ws;                   // 64*8*6400 f32 = 13.1 MB (aliases semb)
  __bf16* Pg    = (__bf16*)(ws + 20971520);     // aliases wcat (dead after gemm)

  cvt_all<<<9412, 256, 0, stream>>>(sem, Wq_w, Wk_w, Wa_w, semb, wcat);
  gemm_fused<<<1360, 256, 0, stream>>>(semb, wcat, Wq_b, Wk_b, Wa_b, Qb, Kb, adj);
  attn_s<<<512, 256, 0, stream>>>(Qb, Kb, Spart);
  attn_soft<<<64, 256, 0, stream>>>(Spart, mask, Pg);
  attn_pv<<<256, 256, 0, stream>>>(Pg, features, adj, out);
}

// Round 13
// 160.304 us; speedup vs baseline: 1.0754x; 1.0754x over previous
//
#include <hip/hip_runtime.h>

typedef __bf16 bf16x8 __attribute__((ext_vector_type(8)));
typedef float f32x4 __attribute__((ext_vector_type(4)));

#define AS1 __attribute__((address_space(1)))
#define AS3 __attribute__((address_space(3)))

__device__ __forceinline__ void gload_lds16(const void* g, void* l) {
  __builtin_amdgcn_global_load_lds((const AS1 void*)g, (AS3 void*)l, 16, 0, 0);
}

#define MFMA16(a, b, c) __builtin_amdgcn_mfma_f32_16x16x32_bf16((a), (b), (c), 0, 0, 0)

// ---------------------------------------------------------------- fp32 -> bf16 (all 4 tensors, grid-stride)
__global__ __launch_bounds__(256)
void cvt_all(const float* __restrict__ sem, const float* __restrict__ wq,
             const float* __restrict__ wk, const float* __restrict__ wa,
             __bf16* __restrict__ semb, __bf16* __restrict__ wcat) {
  for (int i = blockIdx.x * 256 + threadIdx.x; i < 2409472; i += 2048 * 256) {
    const float* in;
    __bf16* out;
    int j;
    if (i < 1310720) { in = sem; out = semb; j = i; }
    else if (i < 1835008) { in = wq; out = wcat; j = i - 1310720; }
    else if (i < 2359296) { in = wk; out = wcat + 4194304; j = i - 1835008; }
    else { in = wa; out = wcat + 8388608; j = i - 2359296; }
    const float4* p = (const float4*)in;
    float4 a = p[2 * j], b = p[2 * j + 1];
    bf16x8 v;
    v[0] = (__bf16)a.x; v[1] = (__bf16)a.y; v[2] = (__bf16)a.z; v[3] = (__bf16)a.w;
    v[4] = (__bf16)b.x; v[5] = (__bf16)b.y; v[6] = (__bf16)b.z; v[7] = (__bf16)b.w;
    *(bf16x8*)(out + (size_t)j * 8) = v;
  }
}

// ---------------------------------------------------------------- fused projection GEMM, 192x128 tiles (r6/r11-proven)
// C[5184(pad),4352] = semb[5120,2048] @ Wcat[4292,2048]^T.
// cols [0,2048)->Qb bf16 +qb; [2048,4096)->Kb bf16 +kb; [4096,4292)->adj sigmoid.
// 512 thr = 8 waves (4M x 2N), wave tile 48x64. BK=64, 32 iters.
// LDS = 80 KiB exactly (A dbuf 2x24 KiB + B dbuf 2x16 KiB) -> 2 blocks/CU = 16 waves/CU.
// This exact config beat 6 structural variants (r7-r10, r12); do not perturb single axes.
__global__ __launch_bounds__(512, 4)
void gemm_fused(const __bf16* __restrict__ A, const __bf16* __restrict__ B,
                const float* __restrict__ qbias, const float* __restrict__ kbias,
                const float* __restrict__ abias, __bf16* __restrict__ Qo,
                __bf16* __restrict__ Ko, float* __restrict__ adj) {
  __shared__ char smem[81920];
  char* smc = smem;
  // bijective XCD chunking (nwg=918, q=114, r=6) + 8-wide tn-band, tm-major in band
  const int bid = blockIdx.x;
  const int xcd = bid & 7, sidx = bid >> 3;
  const int wgid = (xcd < 6 ? xcd * 115 : 690 + (xcd - 6) * 114) + sidx;
  int tm, tn;
  if (wgid < 864) {
    const int band = wgid / 216, rem = wgid % 216;
    tm = rem >> 3;
    tn = band * 8 + (rem & 7);
  } else {
    const int rem = wgid - 864;
    tm = rem >> 1;
    tn = 32 + (rem & 1);
  }

  const int t = threadIdx.x;
  const int lane = t & 63;
  const int w = t >> 6, wm = w >> 1, wn = w & 1;

  // staging constants (linear LDS dest; swizzle folded into global source column)
  const int r0 = t >> 3;                       // 0..63
  const int colx = ((t & 7) ^ (r0 & 7)) * 8;   // pre-swizzled source column (elements)
  const int t16 = t * 16;

#define STAGE_A(kk, pb) do {                                                 \
    char* dstA = smc + (pb) * 24576 + t16;                                   \
    int gr0 = tm * 192 + r0;        gr0 = gr0 < 5120 ? gr0 : 5119;           \
    int gr1 = tm * 192 + 64 + r0;   gr1 = gr1 < 5120 ? gr1 : 5119;           \
    int gr2 = tm * 192 + 128 + r0;  gr2 = gr2 < 5120 ? gr2 : 5119;           \
    gload_lds16(A + (size_t)gr0 * 2048 + (kk) * 64 + colx, dstA);            \
    gload_lds16(A + (size_t)gr1 * 2048 + (kk) * 64 + colx, dstA + 8192);     \
    gload_lds16(A + (size_t)gr2 * 2048 + (kk) * 64 + colx, dstA + 16384);    \
  } while (0)

#define STAGE_B(kk, pb) do {                                                 \
    char* dstB = smc + 49152 + (pb) * 16384 + t16;                           \
    int gr0 = tn * 128 + r0;        gr0 = gr0 < 4292 ? gr0 : 4291;           \
    int gr1 = tn * 128 + 64 + r0;   gr1 = gr1 < 4292 ? gr1 : 4291;           \
    gload_lds16(B + (size_t)gr0 * 2048 + (kk) * 64 + colx, dstB);            \
    gload_lds16(B + (size_t)gr1 * 2048 + (kk) * 64 + colx, dstB + 8192);     \
  } while (0)

  // fragment-read constants (swizzled ds_read)
  const int rbase = (lane & 15) * 128;
  const int g16 = (lane >> 4) * 16;
  const int x16 = (lane & 7) << 4;
  const int aoff = wm * 6144 + rbase;   // wm*48 rows * 128B
  const int boff = wn * 8192 + rbase;   // wn*64 rows * 128B

#define LDA(ab, m, kh) (*(const bf16x8*)((ab) + aoff + (m) * 2048 + ((((kh) * 64) + g16) ^ x16)))
#define LDB(bb, n, kh) (*(const bf16x8*)((bb) + boff + (n) * 2048 + ((((kh) * 64) + g16) ^ x16)))

  f32x4 acc[3][4];
#pragma unroll
  for (int m = 0; m < 3; ++m)
#pragma unroll
    for (int n = 0; n < 4; ++n) acc[m][n] = (f32x4){0.f, 0.f, 0.f, 0.f};

  // prologue: tile 0
  STAGE_A(0, 0); STAGE_B(0, 0);
  asm volatile("s_waitcnt vmcnt(0)" ::: "memory");
  __builtin_amdgcn_s_barrier();

  for (int j = 0; j < 32; ++j) {
    char* Ab = smc + (j & 1) * 24576;
    char* Bb = smc + 49152 + (j & 1) * 16384;
    bf16x8 af[3][2], bf[2][2], bg[2][2];
    // frags for cluster 1
#pragma unroll
    for (int m = 0; m < 3; ++m) { af[m][0] = LDA(Ab, m, 0); af[m][1] = LDA(Ab, m, 1); }
#pragma unroll
    for (int n = 0; n < 2; ++n) { bf[n][0] = LDB(Bb, n, 0); bf[n][1] = LDB(Bb, n, 1); }
    // stage next tile into other buffer
    if (j < 31) { STAGE_A(j + 1, (j + 1) & 1); STAGE_B(j + 1, (j + 1) & 1); }
    __builtin_amdgcn_s_setprio(1);
#pragma unroll
    for (int m = 0; m < 3; ++m)
#pragma unroll
      for (int n = 0; n < 2; ++n) {
        acc[m][n] = MFMA16(af[m][0], bf[n][0], acc[m][n]);
        acc[m][n] = MFMA16(af[m][1], bf[n][1], acc[m][n]);
      }
    __builtin_amdgcn_s_setprio(0);
    // frags + cluster 2
#pragma unroll
    for (int n = 0; n < 2; ++n) { bg[n][0] = LDB(Bb, n + 2, 0); bg[n][1] = LDB(Bb, n + 2, 1); }
    __builtin_amdgcn_s_setprio(1);
#pragma unroll
    for (int m = 0; m < 3; ++m)
#pragma unroll
      for (int n = 0; n < 2; ++n) {
        acc[m][n + 2] = MFMA16(af[m][0], bg[n][0], acc[m][n + 2]);
        acc[m][n + 2] = MFMA16(af[m][1], bg[n][1], acc[m][n + 2]);
      }
    __builtin_amdgcn_s_setprio(0);
    if (j < 31) asm volatile("s_waitcnt vmcnt(0)" ::: "memory");
    __builtin_amdgcn_s_barrier();
  }

  // ---- epilogue
  if (tn < 32) {
    // bias-add + bf16 into LDS [192][136], then coalesced 16B row-major stores
    __bf16* so = (__bf16*)smc;
    const float* bias = (tn < 16) ? (qbias + tn * 128) : (kbias + (tn - 16) * 128);
#pragma unroll
    for (int n = 0; n < 4; ++n) {
      const int colb = wn * 64 + n * 16 + (lane & 15);
      const float bv = bias[colb];
#pragma unroll
      for (int m = 0; m < 3; ++m) {
        const int rw = wm * 48 + m * 16 + (lane >> 4) * 4;
#pragma unroll
        for (int jj = 0; jj < 4; ++jj)
          so[(rw + jj) * 136 + colb] = (__bf16)(acc[m][n][jj] + bv);
      }
    }
    __syncthreads();
    __bf16* dst = (tn < 16) ? (Qo + tn * 128) : (Ko + (tn - 16) * 128);
    for (int idx = t; idx < 3072; idx += 512) {  // 192 rows x 16 16B-chunks
      const int row = idx >> 4, c = idx & 15;
      const int grow = tm * 192 + row;
      if (grow < 5120) {
        bf16x8 v = *(const bf16x8*)(so + row * 136 + c * 8);
        *(bf16x8*)(dst + (size_t)grow * 2048 + c * 8) = v;
      }
    }
  } else {
    // adj region: scattered f32 sigmoid stores (small)
#pragma unroll
    for (int n = 0; n < 4; ++n) {
      const int colg = (tn - 32) * 128 + wn * 64 + n * 16 + (lane & 15);
      if (colg < 196) {
        const float bv = abias[colg];
#pragma unroll
        for (int m = 0; m < 3; ++m)
#pragma unroll
          for (int jj = 0; jj < 4; ++jj) {
            const int row = tm * 192 + wm * 48 + m * 16 + (lane >> 4) * 4 + jj;
            if (row < 5120) {
              const float v = acc[m][n][jj] + bv;
              adj[(size_t)row * 196 + colg] = 1.f / (1.f + __expf(-v));
            }
          }
      }
    }
  }
#undef STAGE_A
#undef STAGE_B
#undef LDA
#undef LDB
}

// ---------------------------------------------------------------- attention 1/3: partial S
// grid (64 b x 8 kq): S_part[b][kq] = Q_b[:, kq*256..+256] @ K_b[...]^T  (f32 80x80)
__global__ __launch_bounds__(256)
void attn_s(const __bf16* __restrict__ Qb, const __bf16* __restrict__ Kb,
            float* __restrict__ Spart) {
  __shared__ char smem[81920];
  __bf16* sQ = (__bf16*)smem;            // [80][256]
  __bf16* sK = (__bf16*)(smem + 40960);  // [80][256]
  const int b = blockIdx.x >> 3, kq = blockIdx.x & 7;
  const int kc = kq * 256;
  const int t = threadIdx.x, lane = t & 63, w = t >> 6;
  const __bf16* Qbase = Qb + (size_t)b * 163840;
  const __bf16* Kbase = Kb + (size_t)b * 163840;

#pragma unroll
  for (int s = 0; s < 10; ++s) {
    const int i = t + s * 256;
    const int row = i >> 5, cb = i & 31;
    gload_lds16(Qbase + (size_t)row * 2048 + kc + cb * 8, sQ + i * 8);
  }
#pragma unroll
  for (int s = 0; s < 10; ++s) {
    const int i = t + s * 256;
    const int row = i >> 5, cb = i & 31;
    gload_lds16(Kbase + (size_t)row * 2048 + kc + cb * 8, sK + i * 8);
  }
  __syncthreads();

  f32x4 acc[7];
#pragma unroll
  for (int u = 0; u < 7; ++u) acc[u] = (f32x4){0.f, 0.f, 0.f, 0.f};
#pragma unroll
  for (int u = 0; u < 7; ++u) {
    const int tl = w + u * 4;
    if (tl < 25) {
      const int qi = tl / 5, kj = tl % 5;
#pragma unroll
      for (int k0 = 0; k0 < 256; k0 += 32) {
        bf16x8 a = *(const bf16x8*)(sQ + (qi * 16 + (lane & 15)) * 256 + k0 + (lane >> 4) * 8);
        bf16x8 kk = *(const bf16x8*)(sK + (kj * 16 + (lane & 15)) * 256 + k0 + (lane >> 4) * 8);
        acc[u] = MFMA16(a, kk, acc[u]);
      }
    }
  }
  float* Sp = Spart + (size_t)(b * 8 + kq) * 6400;
#pragma unroll
  for (int u = 0; u < 7; ++u) {
    const int tl = w + u * 4;
    if (tl < 25) {
      const int qi = tl / 5, kj = tl % 5;
#pragma unroll
      for (int jj = 0; jj < 4; ++jj) {
        const int r = qi * 16 + (lane >> 4) * 4 + jj;
        const int c = kj * 16 + (lane & 15);
        Sp[r * 80 + c] = acc[u][jj];
      }
    }
  }
}

// ---------------------------------------------------------------- attention 2/3: softmax
// grid 64: sum 8 partials, softmax(S*scale*mask), write P bf16 [80][96] (zero-padded)
__global__ __launch_bounds__(256)
void attn_soft(const float* __restrict__ Spart, const float* __restrict__ mask,
               __bf16* __restrict__ Pg) {
  __shared__ float S[80 * 81];
  const int b = blockIdx.x, t = threadIdx.x;
  const float* Sp = Spart + (size_t)b * 8 * 6400;
  for (int idx = t; idx < 6400; idx += 256) {
    float s = 0.f;
#pragma unroll
    for (int p = 0; p < 8; ++p) s += Sp[p * 6400 + idx];
    const int r = idx / 80, c = idx - r * 80;
    S[r * 81 + c] = s;
  }
  __syncthreads();
  if (t < 80) {
    const float scale = 0.02209708691207961f;  // 1/sqrt(2048)
    float mx = -1e30f;
    for (int k = 0; k < 80; ++k) {
      float v = S[t * 81 + k] * scale * mask[t * 80 + k];
      S[t * 81 + k] = v;
      mx = fmaxf(mx, v);
    }
    float sum = 0.f;
    for (int k = 0; k < 80; ++k) {
      float e = __expf(S[t * 81 + k] - mx);
      S[t * 81 + k] = e;
      sum += e;
    }
    const float r = 1.f / sum;
    __bf16* Pr = Pg + (size_t)b * 7680 + t * 96;
    for (int k = 0; k < 80; ++k) Pr[k] = (__bf16)(S[t * 81 + k] * r);
    for (int k = 80; k < 96; ++k) Pr[k] = (__bf16)0.f;
  }
}

// ---------------------------------------------------------------- attention 3/3: PV + epilogue
__global__ __launch_bounds__(256)
void attn_pv(const __bf16* __restrict__ Pg, const float* __restrict__ feats,
             const float* __restrict__ adj, float* __restrict__ out) {
  __shared__ __bf16 Ft[64 * 104];
  const int b = blockIdx.x >> 2, hq = blockIdx.x & 3;
  const int hb = hq * 49;
  const int t = threadIdx.x, lane = t & 63, w = t >> 6;
  for (int idx = t; idx < 4704; idx += 256) {  // 96*49
    const int k = idx / 49, h = idx - k * 49;
    Ft[h * 104 + k] = (k < 80) ? (__bf16)feats[(size_t)b * 15680 + k * 196 + hb + h]
                               : (__bf16)0.f;
  }
  __syncthreads();
  const __bf16* Pb = Pg + (size_t)b * 7680;
#pragma unroll
  for (int u = 0; u < 5; ++u) {
    const int tl = w + u * 4;  // 0..19
    const int ci = tl >> 2, hj = tl & 3;
    f32x4 a2 = (f32x4){0.f, 0.f, 0.f, 0.f};
#pragma unroll
    for (int k0 = 0; k0 < 96; k0 += 32) {
      bf16x8 pa = *(const bf16x8*)(Pb + (ci * 16 + (lane & 15)) * 96 + k0 + (lane >> 4) * 8);
      bf16x8 fb = *(const bf16x8*)(Ft + (hj * 16 + (lane & 15)) * 104 + k0 + (lane >> 4) * 8);
      a2 = MFMA16(pa, fb, a2);
    }
#pragma unroll
    for (int jj = 0; jj < 4; ++jj) {
      const int c = ci * 16 + (lane >> 4) * 4 + jj;
      const int h2 = hj * 16 + (lane & 15);
      if (h2 < 49) {
        const size_t o = (size_t)b * 15680 + (size_t)c * 196 + hb + h2;
        out[o] = (feats[o] + a2[jj]) * adj[o];
      }
    }
  }
}

// ---------------------------------------------------------------- launch
extern "C" void kernel_launch(void* const* d_in, const int* in_sizes, int n_in,
                              void* d_out, int out_size, void* d_ws, size_t ws_size,
                              hipStream_t stream) {
  const float* features = (const float*)d_in[0];
  const float* sem      = (const float*)d_in[1];
  const float* mask     = (const float*)d_in[2];
  const float* Wq_w     = (const float*)d_in[3];
  const float* Wq_b     = (const float*)d_in[4];
  const float* Wk_w     = (const float*)d_in[5];
  const float* Wk_b     = (const float*)d_in[6];
  const float* Wa_w     = (const float*)d_in[7];
  const float* Wa_b     = (const float*)d_in[8];
  float* out = (float*)d_out;

  char* ws = (char*)d_ws;
  __bf16* semb = (__bf16*)ws;                   // 5120x2048 bf16
  __bf16* wcat = (__bf16*)(ws + 20971520);      // 4292x2048 bf16
  __bf16* Qb   = (__bf16*)(ws + 38551552);
  __bf16* Kb   = (__bf16*)(ws + 59523072);
  float*  adj  = (float*)(ws + 80494592);       // 5120x196 f32 (total 84.5 MB)
  float*  Spart = (float*)ws;                   // 64*8*6400 f32 = 13.1 MB (aliases semb)
  __bf16* Pg    = (__bf16*)(ws + 20971520);     // aliases wcat (dead after gemm)

  cvt_all<<<2048, 256, 0, stream>>>(sem, Wq_w, Wk_w, Wa_w, semb, wcat);
  gemm_fused<<<918, 512, 0, stream>>>(semb, wcat, Wq_b, Wk_b, Wa_b, Qb, Kb, adj);
  attn_s<<<512, 256, 0, stream>>>(Qb, Kb, Spart);
  attn_soft<<<64, 256, 0, stream>>>(Spart, mask, Pg);
  attn_pv<<<256, 256, 0, stream>>>(Pg, features, adj, out);
}